// Round 2
// baseline (124.468 us; speedup 1.0000x reference)
//
#include <hip/hip_runtime.h>

// change[i] (i>=1) ∝ (g(i-3) - g(i+2))^2   with g(k)=f[k] zero-padded; change[0]=0
// out[i] = (1 - change[i]/S)^5 * f[i],  S = sum(change)
// The 1/5 conv scaling cancels in change[i]/S, so we accumulate unscaled d^2.
//
// R7 = R6 (memset+atomic path removed; 2 dispatches) with workspace hardening:
//  - reduce grid is clamped at runtime so partials[] always fits ws_size
//    (R6 assumed 8 KB of workspace; if the harness gives less, its plain
//    stores overflowed d_ws -> corrupted adjacent buffers).
//  - reduce blocks write partials with PLAIN stores (no init, no atomics).
//  - finalize block-reduces the partials itself (runtime count), hidden
//    under its 12 outstanding float4 loads of f.

#define BLOCK 256
#define RGRID_MAX 2048

typedef __attribute__((ext_vector_type(4))) float vfloat4;

__device__ __forceinline__ float change_term(const float* __restrict__ f, long long i, long long n) {
    if (i < 1) return 0.0f;
    float a = (i >= 3)    ? f[i - 3] : 0.0f;
    float b = (i + 2 < n) ? f[i + 2] : 0.0f;
    float d = a - b;
    return d * d;
}

__device__ __forceinline__ float pow5(float t) {
    float t2 = t * t;
    float t4 = t2 * t2;
    return t4 * t;
}

// terms for vector v given p=fv[v-1], c=fv[v], q=fv[v+1]; element j=4v+k uses
// a=f[j-3], b=f[j+2]
__device__ __forceinline__ float vec_terms(float4 p, float4 c, float4 q) {
    float d0 = p.y - c.z;
    float d1 = p.z - c.w;
    float d2 = p.w - q.x;
    float d3 = c.x - q.y;
    return d0 * d0 + d1 * d1 + d2 * d2 + d3 * d3;
}

__device__ __forceinline__ vfloat4 vec_out(float4 p, float4 c, float4 q, float inv) {
    float d0 = p.y - c.z;
    float d1 = p.z - c.w;
    float d2 = p.w - q.x;
    float d3 = c.x - q.y;
    vfloat4 o;
    o.x = pow5(1.0f - d0 * d0 * inv) * c.x;
    o.y = pow5(1.0f - d1 * d1 * inv) * c.y;
    o.z = pow5(1.0f - d2 * d2 * inv) * c.z;
    o.w = pow5(1.0f - d3 * d3 * inv) * c.w;
    return o;
}

__global__ __launch_bounds__(BLOCK)
void reduce_change_kernel(const float* __restrict__ f, int nvec, long long n,
                          float* __restrict__ partials) {
    const float4* __restrict__ fv = (const float4*)f;
    const int T = gridDim.x * BLOCK;
    const int tid = blockIdx.x * BLOCK + threadIdx.x;
    const int M = nvec - 2;  // interior vectors: v = 1 + idx, idx in [0, M)
    float acc = 0.0f;

    int idx = tid;
    // unrolled-by-4: 12 independent, perfectly-coalesced float4 loads in flight
    for (; idx + 3 * T < M; idx += 4 * T) {
        float4 p[4], c[4], q[4];
        #pragma unroll
        for (int u = 0; u < 4; ++u) {
            int v = 1 + idx + u * T;
            p[u] = fv[v - 1];
            c[u] = fv[v];
            q[u] = fv[v + 1];
        }
        #pragma unroll
        for (int u = 0; u < 4; ++u)
            acc += vec_terms(p[u], c[u], q[u]);
    }
    for (; idx < M; idx += T) {
        int v = 1 + idx;
        acc += vec_terms(fv[v - 1], fv[v], fv[v + 1]);
    }
    if (tid == 0) {
        #pragma unroll
        for (int k = 0; k < 4; ++k) acc += change_term(f, k, n);
        long long j0 = n - 4;
        #pragma unroll
        for (int k = 0; k < 4; ++k) acc += change_term(f, j0 + k, n);
    }

    // wave (64-lane) reduction
    #pragma unroll
    for (int off = 32; off > 0; off >>= 1)
        acc += __shfl_down(acc, off, 64);
    __shared__ float smem[4];
    int lane = threadIdx.x & 63;
    int wave = threadIdx.x >> 6;
    if (lane == 0) smem[wave] = acc;
    __syncthreads();
    if (threadIdx.x == 0)
        partials[blockIdx.x] = smem[0] + smem[1] + smem[2] + smem[3];  // plain store, no init needed
}

__global__ __launch_bounds__(BLOCK)
void finalize_kernel(const float* __restrict__ f, int nvec, long long n,
                     const float* __restrict__ partials, int npart,
                     float* __restrict__ out) {
    const float4* __restrict__ fv = (const float4*)f;
    vfloat4* __restrict__ ov = (vfloat4*)out;
    const int M = nvec - 2;       // interior vectors
    const int T = (M + 3) >> 2;   // 4 strided interior vectors per thread
    const int tid = blockIdx.x * BLOCK + threadIdx.x;

    // ---- issue all 12 f loads first (latency hides under the partial reduction) ----
    bool active = tid < T;
    int i0 = active ? tid : 0;
    bool ok1 = active && (i0 + 1 * T < M);
    bool ok2 = active && (i0 + 2 * T < M);
    bool ok3 = active && (i0 + 3 * T < M);
    int v0 = 1 + i0;
    int v1 = ok1 ? v0 + T : v0;
    int v2 = ok2 ? v1 + T : v1;
    int v3 = ok3 ? v2 + T : v2;
    float4 p0 = fv[v0 - 1], c0 = fv[v0], q0 = fv[v0 + 1];
    float4 p1 = fv[v1 - 1], c1 = fv[v1], q1 = fv[v1 + 1];
    float4 p2 = fv[v2 - 1], c2 = fv[v2], q2 = fv[v2 + 1];
    float4 p3 = fv[v3 - 1], c3 = fv[v3], q3 = fv[v3 + 1];

    // ---- block-reduce the npart partial sums (coalesced, L2-resident) ----
    float s = 0.0f;
    for (int k = threadIdx.x; k < npart; k += BLOCK)
        s += partials[k];
    #pragma unroll
    for (int off = 32; off > 0; off >>= 1)
        s += __shfl_down(s, off, 64);
    __shared__ float smem[4];
    __shared__ float stot;
    int lane = threadIdx.x & 63;
    int wave = threadIdx.x >> 6;
    if (lane == 0) smem[wave] = s;
    __syncthreads();
    if (threadIdx.x == 0) stot = smem[0] + smem[1] + smem[2] + smem[3];
    __syncthreads();
    float inv = 1.0f / stot;

    // ---- compute + nontemporal stores (write-once data) ----
    if (active) {
        __builtin_nontemporal_store(vec_out(p0, c0, q0, inv), &ov[v0]);
        if (ok1) __builtin_nontemporal_store(vec_out(p1, c1, q1, inv), &ov[v1]);
        if (ok2) __builtin_nontemporal_store(vec_out(p2, c2, q2, inv), &ov[v2]);
        if (ok3) __builtin_nontemporal_store(vec_out(p3, c3, q3, inv), &ov[v3]);
    }
    if (tid == 0) {
        // edge vectors v=0 and v=nvec-1, scalar
        #pragma unroll
        for (int k = 0; k < 4; ++k) {
            float cge = change_term(f, k, n) * inv;
            out[k] = pow5(1.0f - cge) * f[k];
        }
        long long j0 = n - 4;
        #pragma unroll
        for (int k = 0; k < 4; ++k) {
            long long j = j0 + k;
            float cge = change_term(f, j, n) * inv;
            out[j] = pow5(1.0f - cge) * f[j];
        }
    }
}

extern "C" void kernel_launch(void* const* d_in, const int* in_sizes, int n_in,
                              void* d_out, int out_size, void* d_ws, size_t ws_size,
                              hipStream_t stream) {
    const float* f = (const float*)d_in[0];
    float* out = (float*)d_out;
    float* partials = (float*)d_ws;
    long long n = (long long)in_sizes[0];
    int nvec = (int)(n / 4);  // n = 2^24, divisible by 4

    // clamp reduce grid so partials[] (rgrid floats) always fits in ws_size
    int rgrid = RGRID_MAX;
    if (ws_size > 0 && (size_t)rgrid * sizeof(float) > ws_size) {
        rgrid = (int)(ws_size / sizeof(float));
        if (rgrid > RGRID_MAX) rgrid = RGRID_MAX;
        if (rgrid < 1) rgrid = 1;
    }

    reduce_change_kernel<<<rgrid, BLOCK, 0, stream>>>(f, nvec, n, partials);

    int M = nvec - 2;
    int T = (M + 3) >> 2;
    int fgrid = (T + BLOCK - 1) / BLOCK;
    finalize_kernel<<<fgrid, BLOCK, 0, stream>>>(f, nvec, n, partials, rgrid, out);
}